// Round 1
// baseline (2703.316 us; speedup 1.0000x reference)
//
#include <hip/hip_runtime.h>
#include <hip/hip_bf16.h>

#define N_NODES 50000
#define E_EDGES 1600000
#define D_IN 64
#define H_DIM 128

static constexpr float BN_EPS_C = 1e-5f;

__device__ inline void atomAddF(float* p, float v) {
#if defined(__HIP_PLATFORM_AMD__)
  unsafeAtomicAdd(p, v);   // native global_atomic_add_f32 on gfx950
#else
  atomicAdd(p, v);
#endif
}

// M_l = w_neigh_l @ w_edge_l  -> [128, 64]
__global__ __launch_bounds__(256) void mk_kernel(
    const float* __restrict__ wn0, const float* __restrict__ we0,
    const float* __restrict__ wn1, const float* __restrict__ we1,
    float* __restrict__ M0, float* __restrict__ M1) {
  int t = blockIdx.x * 256 + threadIdx.x;   // 16384 total
  int l = t >> 13;
  int rem = t & 8191;
  int o = rem >> 6, d = rem & 63;
  const float* wn = l ? wn1 : wn0;
  const float* we = l ? we1 : we0;
  float acc = 0.f;
#pragma unroll 8
  for (int k = 0; k < 128; ++k) acc = fmaf(wn[o * 128 + k], we[k * 64 + d], acc);
  (l ? M1 : M0)[o * 64 + d] = acc;
}

// S[dst] += edge_attr[e], deg[dst] += 1.   16 threads per edge, float4 each.
__global__ __launch_bounds__(256) void scatter_kernel(
    const float* __restrict__ ea, const int* __restrict__ ei,
    float* __restrict__ S, float* __restrict__ deg) {
  int gid = blockIdx.x * 256 + threadIdx.x;   // exactly E*16 threads
  int e = gid >> 4;
  int c = (gid & 15) * 4;
  int dst = ei[E_EDGES + e];                  // edge_index row 1
  float4 v = *(const float4*)(ea + (size_t)e * 64 + c);
  float* s = S + (size_t)dst * 64 + c;
  atomAddF(s + 0, v.x);
  atomAddF(s + 1, v.y);
  atomAddF(s + 2, v.z);
  atomAddF(s + 3, v.w);
  if (c == 0) atomAddF(deg + dst, 1.0f);
}

// Generic node-level GEMM: out[n][o] = epilogue( sum_i in[n][i] * W[o][i] )
// in row = [ inA (KA) | S[n]/max(deg,1) (64, if HAS_S) ],  W row = [ W0 | W1 ].
// 256 threads, 32 nodes/block, thread: 2 nodes x 8 outputs.
template <int KIN, bool HAS_S>
__global__ __launch_bounds__(256) void node_gemm(
    const float* __restrict__ inA,
    const float* __restrict__ S, const float* __restrict__ deg,
    const float* __restrict__ W0, int w0_stride,
    const float* __restrict__ W1,
    const float* __restrict__ bias,
    const float* __restrict__ bn_g, const float* __restrict__ bn_b,
    const float* __restrict__ bn_m, const float* __restrict__ bn_v,
    int do_relu,
    float* __restrict__ out) {
  constexpr int KA = HAS_S ? (KIN - 64) : KIN;
  constexpr int KP = KIN + 4;                 // padded row stride (dwords)
  extern __shared__ float lds[];
  float* w_lds = lds;                          // [128][KP]
  float* in_lds = lds + 128 * KP;              // [32][KP]
  const int t = threadIdx.x;
  const int node0 = blockIdx.x * 32;

  // ---- stage weights ----
  for (int idx = t; idx < 128 * (KA / 4); idx += 256) {
    int o = idx / (KA / 4), c = idx % (KA / 4);
    float4 v = *(const float4*)(W0 + (size_t)o * w0_stride + 4 * c);
    *(float4*)&w_lds[o * KP + 4 * c] = v;
  }
  if (HAS_S) {
    for (int idx = t; idx < 128 * 16; idx += 256) {
      int o = idx >> 4, c = idx & 15;
      float4 v = *(const float4*)(W1 + o * 64 + 4 * c);
      *(float4*)&w_lds[o * KP + KA + 4 * c] = v;
    }
  }
  // ---- stage inputs ----
  for (int idx = t; idx < 32 * (KA / 4); idx += 256) {
    int n = idx / (KA / 4), c = idx % (KA / 4);
    int node = node0 + n;
    float4 v = make_float4(0.f, 0.f, 0.f, 0.f);
    if (node < N_NODES) v = *(const float4*)(inA + (size_t)node * KA + 4 * c);
    *(float4*)&in_lds[n * KP + 4 * c] = v;
  }
  if (HAS_S) {
    for (int idx = t; idx < 32 * 16; idx += 256) {
      int n = idx >> 4, c = idx & 15;
      int node = node0 + n;
      float4 v = make_float4(0.f, 0.f, 0.f, 0.f);
      if (node < N_NODES) {
        v = *(const float4*)(S + (size_t)node * 64 + 4 * c);
        float r = 1.0f / fmaxf(deg[node], 1.0f);
        v.x *= r; v.y *= r; v.z *= r; v.w *= r;
      }
      *(float4*)&in_lds[n * KP + KA + 4 * c] = v;
    }
  }
  __syncthreads();

  const int ng = t >> 4;   // 0..15 -> nodes ng, ng+16
  const int ol = t & 15;   // outputs o = ol + 16*r, r<8
  float acc[2][8];
#pragma unroll
  for (int q = 0; q < 2; ++q)
#pragma unroll
    for (int r = 0; r < 8; ++r) acc[q][r] = 0.f;

#pragma unroll 4
  for (int i = 0; i < KIN; i += 4) {
    float4 a0 = *(const float4*)&in_lds[ng * KP + i];
    float4 a1 = *(const float4*)&in_lds[(ng + 16) * KP + i];
#pragma unroll
    for (int r = 0; r < 8; ++r) {
      float4 w = *(const float4*)&w_lds[(ol + 16 * r) * KP + i];
      acc[0][r] = fmaf(a0.x, w.x, acc[0][r]);
      acc[0][r] = fmaf(a0.y, w.y, acc[0][r]);
      acc[0][r] = fmaf(a0.z, w.z, acc[0][r]);
      acc[0][r] = fmaf(a0.w, w.w, acc[0][r]);
      acc[1][r] = fmaf(a1.x, w.x, acc[1][r]);
      acc[1][r] = fmaf(a1.y, w.y, acc[1][r]);
      acc[1][r] = fmaf(a1.z, w.z, acc[1][r]);
      acc[1][r] = fmaf(a1.w, w.w, acc[1][r]);
    }
  }

  // ---- epilogue: +bias, BN (eval), ReLU ----
#pragma unroll
  for (int r = 0; r < 8; ++r) {
    int o = ol + 16 * r;
    float add = bias ? bias[o] : 0.f;
    float scale = 1.f, shift = 0.f;
    if (bn_g) {
      float sc = bn_g[o] * rsqrtf(bn_v[o] + BN_EPS_C);
      scale = sc;
      shift = bn_b[o] - bn_m[o] * sc;
    }
#pragma unroll
    for (int q = 0; q < 2; ++q) {
      int node = node0 + ng + 16 * q;
      if (node < N_NODES) {
        float h = acc[q][r] + add;
        h = fmaf(h, scale, shift);
        if (do_relu) h = fmaxf(h, 0.f);
        out[(size_t)node * 128 + o] = h;
      }
    }
  }
}

// out[e] = relu(P[a] + Q[b]) @ wc2.T + bc2.   One wave per edge.
__global__ __launch_bounds__(256) void edge_cls(
    const float* __restrict__ P, const float* __restrict__ Q,
    const int* __restrict__ eli,
    const float* __restrict__ wc2, const float* __restrict__ bc2,
    float* __restrict__ out) {
  int wid = (blockIdx.x * 256 + threadIdx.x) >> 6;   // edge id, exactly E waves
  int lane = threadIdx.x & 63;
  int a = eli[wid];
  int b = eli[E_EDGES + wid];
  float2 p = *(const float2*)(P + (size_t)a * 128 + lane * 2);
  float2 q = *(const float2*)(Q + (size_t)b * 128 + lane * 2);
  float h0 = fmaxf(p.x + q.x, 0.f);
  float h1 = fmaxf(p.y + q.y, 0.f);
  float2 w0 = *(const float2*)(wc2 + lane * 2);
  float2 w1 = *(const float2*)(wc2 + 128 + lane * 2);
  float o0 = h0 * w0.x + h1 * w0.y;
  float o1 = h0 * w1.x + h1 * w1.y;
#pragma unroll
  for (int m = 32; m > 0; m >>= 1) {
    o0 += __shfl_xor(o0, m);
    o1 += __shfl_xor(o1, m);
  }
  if (lane == 0) {
    float2 res = make_float2(o0 + bc2[0], o1 + bc2[1]);
    *(float2*)(out + (size_t)wid * 2) = res;
  }
}

extern "C" void kernel_launch(void* const* d_in, const int* in_sizes, int n_in,
                              void* d_out, int out_size, void* d_ws, size_t ws_size,
                              hipStream_t stream) {
  const float* x   = (const float*)d_in[0];
  const int*   ei  = (const int*)d_in[1];
  const float* ea  = (const float*)d_in[2];
  const int*   eli = (const int*)d_in[3];
  const float* w_self_0 = (const float*)d_in[4];
  const float* w_neigh_0 = (const float*)d_in[5];
  const float* w_edge_0 = (const float*)d_in[6];
  const float* b_0 = (const float*)d_in[7];
  const float* g0 = (const float*)d_in[8];
  const float* bb0 = (const float*)d_in[9];
  const float* m0 = (const float*)d_in[10];
  const float* v0 = (const float*)d_in[11];
  const float* w_self_1 = (const float*)d_in[12];
  const float* w_neigh_1 = (const float*)d_in[13];
  const float* w_edge_1 = (const float*)d_in[14];
  const float* b_1 = (const float*)d_in[15];
  const float* g1 = (const float*)d_in[16];
  const float* bb1 = (const float*)d_in[17];
  const float* m1 = (const float*)d_in[18];
  const float* v1 = (const float*)d_in[19];
  const float* wc1 = (const float*)d_in[20];
  const float* bc1 = (const float*)d_in[21];
  const float* wc2 = (const float*)d_in[22];
  const float* bc2 = (const float*)d_in[23];

  float* ws = (float*)d_ws;
  // workspace layout (floats); later buffers overlay dead earlier ones
  float* S   = ws;                    // [N,64]   @ 0        (3,200,000)
  float* deg = ws + 3200000;          // [N]               (50,000)
  float* M0  = ws + 3250000;          // [128,64]
  float* M1  = ws + 3258192;          // [128,64]
  float* h0  = ws + 3266384;          // [N,128] -> end 9,666,384
  float* h1  = ws + 12800000;         // [N,128] -> end 19,200,000
  float* P   = ws;                    // overlays S/deg/M (dead after h1)
  float* Q   = ws + 6400000;          // overlays h0 tail (dead after h1)

  // zero S + deg
  hipMemsetAsync(S, 0, 13000000, stream);

  mk_kernel<<<64, 256, 0, stream>>>(w_neigh_0, w_edge_0, w_neigh_1, w_edge_1, M0, M1);

  scatter_kernel<<<E_EDGES * 16 / 256, 256, 0, stream>>>(ea, ei, S, deg);

  const int ngrid = (N_NODES + 31) / 32;   // 1563
  // layer 0: h0 = relu(bn0( x@Ws0.T + Abar@M0.T + b0 ))
  node_gemm<128, true><<<ngrid, 256, 160 * 132 * 4, stream>>>(
      x, S, deg, w_self_0, 64, M0, b_0, g0, bb0, m0, v0, 1, h0);
  // layer 1: h1 = relu(bn1( h0@Ws1.T + Abar@M1.T + b1 ))
  node_gemm<192, true><<<ngrid, 256, 160 * 196 * 4, stream>>>(
      h0, S, deg, w_self_1, 128, M1, b_1, g1, bb1, m1, v1, 1, h1);
  // P = h1 @ wc1[:, :128].T + bc1
  node_gemm<128, false><<<ngrid, 256, 160 * 132 * 4, stream>>>(
      h1, nullptr, nullptr, wc1, 256, nullptr, bc1,
      nullptr, nullptr, nullptr, nullptr, 0, P);
  // Q = h1 @ wc1[:, 128:].T
  node_gemm<128, false><<<ngrid, 256, 160 * 132 * 4, stream>>>(
      h1, nullptr, nullptr, wc1 + 128, 256, nullptr, nullptr,
      nullptr, nullptr, nullptr, nullptr, 0, Q);

  edge_cls<<<E_EDGES / 4, 256, 0, stream>>>(P, Q, eli, wc2, bc2, (float*)d_out);
}

// Round 5
// 1494.050 us; speedup vs baseline: 1.8094x; 1.8094x over previous
//
#include <hip/hip_runtime.h>
#include <hip/hip_bf16.h>

#define N_NODES 50000
#define E_EDGES 1600000
#define D_IN 64
#define H_DIM 128

static constexpr float BN_EPS_C = 1e-5f;

// ---------------- counting sort by dst ----------------

__global__ __launch_bounds__(256) void hist_kernel(
    const int* __restrict__ ei, int* __restrict__ cnt) {
  int e = blockIdx.x * 256 + threadIdx.x;          // exactly E threads
  atomicAdd(&cnt[ei[E_EDGES + e]], 1);
}

// block-local exclusive scan (256 elems/block), emit block sums
__global__ __launch_bounds__(256) void scan1_kernel(
    const int* __restrict__ cnt, int* __restrict__ off, int* __restrict__ bsum) {
  __shared__ int sd[256];
  int tid = threadIdx.x;
  int t = blockIdx.x * 256 + tid;
  int val = (t < N_NODES) ? cnt[t] : 0;
  sd[tid] = val;
  __syncthreads();
#pragma unroll
  for (int d = 1; d < 256; d <<= 1) {
    int add = (tid >= d) ? sd[tid - d] : 0;
    __syncthreads();
    sd[tid] += add;
    __syncthreads();
  }
  if (t < N_NODES) off[t] = sd[tid] - val;         // exclusive, block-local
  if (tid == 255) bsum[blockIdx.x] = sd[255];
}

__global__ __launch_bounds__(256) void scan2_kernel(int* __restrict__ bsum, int nb) {
  __shared__ int sd[256];
  int tid = threadIdx.x;
  int val = (tid < nb) ? bsum[tid] : 0;
  sd[tid] = val;
  __syncthreads();
#pragma unroll
  for (int d = 1; d < 256; d <<= 1) {
    int add = (tid >= d) ? sd[tid - d] : 0;
    __syncthreads();
    sd[tid] += add;
    __syncthreads();
  }
  if (tid < nb) bsum[tid] = sd[tid] - val;         // exclusive block offsets
}

__global__ __launch_bounds__(256) void scan3_kernel(
    int* __restrict__ off, const int* __restrict__ bsum, int* __restrict__ cursor) {
  int t = blockIdx.x * 256 + threadIdx.x;
  if (t < N_NODES) {
    int o = off[t] + bsum[blockIdx.x];
    off[t] = o;
    cursor[t] = o;
  }
  if (t == 0) off[N_NODES] = E_EDGES;
}

__global__ __launch_bounds__(256) void place_kernel(
    const int* __restrict__ ei, int* __restrict__ cursor, int* __restrict__ perm) {
  int e = blockIdx.x * 256 + threadIdx.x;          // exactly E threads
  int dst = ei[E_EDGES + e];
  int pos = atomicAdd(&cursor[dst], 1);
  perm[pos] = e;
}

// One wave per node. 16 lanes per edge-row (float4/lane), 4 rows in flight.
// Sbar[n][:] = (1/max(deg,1)) * sum_{e in n} ea[e][:]
__global__ __launch_bounds__(256) void reduce_kernel(
    const float* __restrict__ ea, const int* __restrict__ perm,
    const int* __restrict__ off, float* __restrict__ Sbar) {
  int wid = (blockIdx.x * 256 + threadIdx.x) >> 6;   // node id
  int lane = threadIdx.x & 63;
  if (wid >= N_NODES) return;
  int s = off[wid];
  int e = off[wid + 1];
  int g = lane >> 4;          // edge slot 0..3
  int c = (lane & 15) * 4;    // dim offset 0..60
  float4 acc = make_float4(0.f, 0.f, 0.f, 0.f);
  for (int i = s + g; i < e; i += 4) {
    int ed = perm[i];
    float4 v = *(const float4*)(ea + (size_t)ed * 64 + c);
    acc.x += v.x; acc.y += v.y; acc.z += v.z; acc.w += v.w;
  }
  // combine the 4 edge-slot groups: lane l with l^16, then l^32
  acc.x += __shfl_xor(acc.x, 16);
  acc.y += __shfl_xor(acc.y, 16);
  acc.z += __shfl_xor(acc.z, 16);
  acc.w += __shfl_xor(acc.w, 16);
  acc.x += __shfl_xor(acc.x, 32);
  acc.y += __shfl_xor(acc.y, 32);
  acc.z += __shfl_xor(acc.z, 32);
  acc.w += __shfl_xor(acc.w, 32);
  if (lane < 16) {
    float r = 1.0f / fmaxf((float)(e - s), 1.0f);
    acc.x *= r; acc.y *= r; acc.z *= r; acc.w *= r;
    *(float4*)(Sbar + (size_t)wid * 64 + c) = acc;
  }
}

// ---------------- dense node-level kernels ----------------

// M_l = w_neigh_l @ w_edge_l  -> [128, 64]
__global__ __launch_bounds__(256) void mk_kernel(
    const float* __restrict__ wn0, const float* __restrict__ we0,
    const float* __restrict__ wn1, const float* __restrict__ we1,
    float* __restrict__ M0, float* __restrict__ M1) {
  int t = blockIdx.x * 256 + threadIdx.x;   // 16384 total
  int l = t >> 13;
  int rem = t & 8191;
  int o = rem >> 6, d = rem & 63;
  const float* wn = l ? wn1 : wn0;
  const float* we = l ? we1 : we0;
  float acc = 0.f;
#pragma unroll 8
  for (int k = 0; k < 128; ++k) acc = fmaf(wn[o * 128 + k], we[k * 64 + d], acc);
  (l ? M1 : M0)[o * 64 + d] = acc;
}

// out[n][o] = epilogue( sum_i in[n][i] * W[o][i] )
// in row = [ inA (KA) | Sbar[n] (64, if HAS_S) ],  W row = [ W0 | W1 ].
template <int KIN, bool HAS_S>
__global__ __launch_bounds__(256) void node_gemm(
    const float* __restrict__ inA,
    const float* __restrict__ Sbar,
    const float* __restrict__ W0, int w0_stride,
    const float* __restrict__ W1,
    const float* __restrict__ bias,
    const float* __restrict__ bn_g, const float* __restrict__ bn_b,
    const float* __restrict__ bn_m, const float* __restrict__ bn_v,
    int do_relu,
    float* __restrict__ out) {
  constexpr int KA = HAS_S ? (KIN - 64) : KIN;
  constexpr int KP = KIN + 4;                 // padded row stride (dwords)
  extern __shared__ float lds[];
  float* w_lds = lds;                          // [128][KP]
  float* in_lds = lds + 128 * KP;              // [32][KP]
  const int t = threadIdx.x;
  const int node0 = blockIdx.x * 32;

  // ---- stage weights ----
  for (int idx = t; idx < 128 * (KA / 4); idx += 256) {
    int o = idx / (KA / 4), c = idx % (KA / 4);
    float4 v = *(const float4*)(W0 + (size_t)o * w0_stride + 4 * c);
    *(float4*)&w_lds[o * KP + 4 * c] = v;
  }
  if (HAS_S) {
    for (int idx = t; idx < 128 * 16; idx += 256) {
      int o = idx >> 4, c = idx & 15;
      float4 v = *(const float4*)(W1 + o * 64 + 4 * c);
      *(float4*)&w_lds[o * KP + KA + 4 * c] = v;
    }
  }
  // ---- stage inputs ----
  for (int idx = t; idx < 32 * (KA / 4); idx += 256) {
    int n = idx / (KA / 4), c = idx % (KA / 4);
    int node = node0 + n;
    float4 v = make_float4(0.f, 0.f, 0.f, 0.f);
    if (node < N_NODES) v = *(const float4*)(inA + (size_t)node * KA + 4 * c);
    *(float4*)&in_lds[n * KP + 4 * c] = v;
  }
  if (HAS_S) {
    for (int idx = t; idx < 32 * 16; idx += 256) {
      int n = idx >> 4, c = idx & 15;
      int node = node0 + n;
      float4 v = make_float4(0.f, 0.f, 0.f, 0.f);
      if (node < N_NODES) v = *(const float4*)(Sbar + (size_t)node * 64 + 4 * c);
      *(float4*)&in_lds[n * KP + KA + 4 * c] = v;
    }
  }
  __syncthreads();

  const int ng = t >> 4;   // 0..15 -> nodes ng, ng+16
  const int ol = t & 15;   // outputs o = ol + 16*r, r<8
  float acc[2][8];
#pragma unroll
  for (int q = 0; q < 2; ++q)
#pragma unroll
    for (int r = 0; r < 8; ++r) acc[q][r] = 0.f;

#pragma unroll 4
  for (int i = 0; i < KIN; i += 4) {
    float4 a0 = *(const float4*)&in_lds[ng * KP + i];
    float4 a1 = *(const float4*)&in_lds[(ng + 16) * KP + i];
#pragma unroll
    for (int r = 0; r < 8; ++r) {
      float4 w = *(const float4*)&w_lds[(ol + 16 * r) * KP + i];
      acc[0][r] = fmaf(a0.x, w.x, acc[0][r]);
      acc[0][r] = fmaf(a0.y, w.y, acc[0][r]);
      acc[0][r] = fmaf(a0.z, w.z, acc[0][r]);
      acc[0][r] = fmaf(a0.w, w.w, acc[0][r]);
      acc[1][r] = fmaf(a1.x, w.x, acc[1][r]);
      acc[1][r] = fmaf(a1.y, w.y, acc[1][r]);
      acc[1][r] = fmaf(a1.z, w.z, acc[1][r]);
      acc[1][r] = fmaf(a1.w, w.w, acc[1][r]);
    }
  }

  // ---- epilogue: +bias, BN (eval), ReLU ----
#pragma unroll
  for (int r = 0; r < 8; ++r) {
    int o = ol + 16 * r;
    float add = bias ? bias[o] : 0.f;
    float scale = 1.f, shift = 0.f;
    if (bn_g) {
      float sc = bn_g[o] * rsqrtf(bn_v[o] + BN_EPS_C);
      scale = sc;
      shift = bn_b[o] - bn_m[o] * sc;
    }
#pragma unroll
    for (int q = 0; q < 2; ++q) {
      int node = node0 + ng + 16 * q;
      if (node < N_NODES) {
        float h = acc[q][r] + add;
        h = fmaf(h, scale, shift);
        if (do_relu) h = fmaxf(h, 0.f);
        out[(size_t)node * 128 + o] = h;
      }
    }
  }
}

// out[e] = relu(P[a] + Q[b]) @ wc2.T + bc2.
// 4 edges per wave, 16 lanes per edge, 8 dims (2x float4) per lane.
__global__ __launch_bounds__(256) void edge_cls(
    const float* __restrict__ P, const float* __restrict__ Q,
    const int* __restrict__ eli,
    const float* __restrict__ wc2, const float* __restrict__ bc2,
    float* __restrict__ out) {
  int wid = (blockIdx.x * 256 + threadIdx.x) >> 6;   // wave id
  int lane = threadIdx.x & 63;
  int g = lane >> 4;                                  // edge slot 0..3
  int l4 = lane & 15;
  int c = l4 * 4;                                     // dims c..c+3, 64+c..64+c+3
  int eid = wid * 4 + g;                              // exactly E edges
  int a = eli[eid];
  int b = eli[E_EDGES + eid];
  float4 pa = *(const float4*)(P + (size_t)a * 128 + c);
  float4 pb = *(const float4*)(P + (size_t)a * 128 + 64 + c);
  float4 qa = *(const float4*)(Q + (size_t)b * 128 + c);
  float4 qb = *(const float4*)(Q + (size_t)b * 128 + 64 + c);
  float4 w0a = *(const float4*)(wc2 + c);
  float4 w0b = *(const float4*)(wc2 + 64 + c);
  float4 w1a = *(const float4*)(wc2 + 128 + c);
  float4 w1b = *(const float4*)(wc2 + 192 + c);
  float o0 = 0.f, o1 = 0.f, h;
  h = fmaxf(pa.x + qa.x, 0.f); o0 = fmaf(h, w0a.x, o0); o1 = fmaf(h, w1a.x, o1);
  h = fmaxf(pa.y + qa.y, 0.f); o0 = fmaf(h, w0a.y, o0); o1 = fmaf(h, w1a.y, o1);
  h = fmaxf(pa.z + qa.z, 0.f); o0 = fmaf(h, w0a.z, o0); o1 = fmaf(h, w1a.z, o1);
  h = fmaxf(pa.w + qa.w, 0.f); o0 = fmaf(h, w0a.w, o0); o1 = fmaf(h, w1a.w, o1);
  h = fmaxf(pb.x + qb.x, 0.f); o0 = fmaf(h, w0b.x, o0); o1 = fmaf(h, w1b.x, o1);
  h = fmaxf(pb.y + qb.y, 0.f); o0 = fmaf(h, w0b.y, o0); o1 = fmaf(h, w1b.y, o1);
  h = fmaxf(pb.z + qb.z, 0.f); o0 = fmaf(h, w0b.z, o0); o1 = fmaf(h, w1b.z, o1);
  h = fmaxf(pb.w + qb.w, 0.f); o0 = fmaf(h, w0b.w, o0); o1 = fmaf(h, w1b.w, o1);
  // reduce within each 16-lane group (xor of bits 0..3 stays in-group)
#pragma unroll
  for (int m = 1; m < 16; m <<= 1) {
    o0 += __shfl_xor(o0, m);
    o1 += __shfl_xor(o1, m);
  }
  if (l4 == 0) {
    float2 res = make_float2(o0 + bc2[0], o1 + bc2[1]);
    *(float2*)(out + (size_t)eid * 2) = res;
  }
}

extern "C" void kernel_launch(void* const* d_in, const int* in_sizes, int n_in,
                              void* d_out, int out_size, void* d_ws, size_t ws_size,
                              hipStream_t stream) {
  const float* x   = (const float*)d_in[0];
  const int*   ei  = (const int*)d_in[1];
  const float* ea  = (const float*)d_in[2];
  const int*   eli = (const int*)d_in[3];
  const float* w_self_0 = (const float*)d_in[4];
  const float* w_neigh_0 = (const float*)d_in[5];
  const float* w_edge_0 = (const float*)d_in[6];
  const float* b_0 = (const float*)d_in[7];
  const float* g0 = (const float*)d_in[8];
  const float* bb0 = (const float*)d_in[9];
  const float* m0 = (const float*)d_in[10];
  const float* v0 = (const float*)d_in[11];
  const float* w_self_1 = (const float*)d_in[12];
  const float* w_neigh_1 = (const float*)d_in[13];
  const float* w_edge_1 = (const float*)d_in[14];
  const float* b_1 = (const float*)d_in[15];
  const float* g1 = (const float*)d_in[16];
  const float* bb1 = (const float*)d_in[17];
  const float* m1 = (const float*)d_in[18];
  const float* v1 = (const float*)d_in[19];
  const float* wc1 = (const float*)d_in[20];
  const float* bc1 = (const float*)d_in[21];
  const float* wc2 = (const float*)d_in[22];
  const float* bc2 = (const float*)d_in[23];

  float* ws = (float*)d_ws;
  int*   wsi = (int*)d_ws;
  // workspace layout (4B units); later buffers overlay dead earlier ones
  int*   perm   = wsi;                  // [E]        @ 0        -> 1,600,000
  int*   cnt    = wsi + 1600000;        // [N]                   -> 1,650,000
  int*   off    = wsi + 1650000;        // [N+1]                 -> 1,700,001
  int*   cursor = wsi + 1700008;        // [N]                   -> 1,750,008
  int*   bsum   = wsi + 1750008;        // [256]                 -> 1,750,264
  float* Sbar   = ws  + 1750272;        // [N,64]                -> 4,950,272
  float* M0     = ws  + 4950272;        // [128,64]
  float* M1     = ws  + 4958464;        // [128,64]              -> 4,966,656
  float* h0     = ws  + 4966656;        // [N,128]               -> 11,366,656
  float* h1     = ws  + 12800000;       // [N,128]               -> 19,200,000
  float* P      = ws;                   // [N,128] overlays sort scratch + Sbar (dead after h1)
  float* Q      = ws  + 6400000;        // [N,128] overlays h0 tail (dead after h1)

  // zero histogram + block sums
  hipMemsetAsync(cnt, 0, 50000 * 4, stream);
  hipMemsetAsync(bsum, 0, 256 * 4, stream);

  mk_kernel<<<64, 256, 0, stream>>>(w_neigh_0, w_edge_0, w_neigh_1, w_edge_1, M0, M1);

  // counting sort by dst + gather reduce
  const int nb_scan = (N_NODES + 255) / 256;       // 196
  hist_kernel<<<E_EDGES / 256, 256, 0, stream>>>(ei, cnt);
  scan1_kernel<<<nb_scan, 256, 0, stream>>>(cnt, off, bsum);
  scan2_kernel<<<1, 256, 0, stream>>>(bsum, nb_scan);
  scan3_kernel<<<nb_scan, 256, 0, stream>>>(off, bsum, cursor);
  place_kernel<<<E_EDGES / 256, 256, 0, stream>>>(ei, cursor, perm);
  reduce_kernel<<<(N_NODES * 64 + 255) / 256, 256, 0, stream>>>(ea, perm, off, Sbar);

  const int ngrid = (N_NODES + 31) / 32;   // 1563
  // layer 0: h0 = relu(bn0( x@Ws0.T + Sbar@M0.T + b0 ))
  node_gemm<128, true><<<ngrid, 256, 160 * 132 * 4, stream>>>(
      x, Sbar, w_self_0, 64, M0, b_0, g0, bb0, m0, v0, 1, h0);
  // layer 1: h1 = relu(bn1( h0@Ws1.T + Sbar@M1.T + b1 ))
  node_gemm<192, true><<<ngrid, 256, 160 * 196 * 4, stream>>>(
      h0, Sbar, w_self_1, 128, M1, b_1, g1, bb1, m1, v1, 1, h1);
  // P = h1 @ wc1[:, :128].T + bc1
  node_gemm<128, false><<<ngrid, 256, 160 * 132 * 4, stream>>>(
      h1, nullptr, wc1, 256, nullptr, bc1,
      nullptr, nullptr, nullptr, nullptr, 0, P);
  // Q = h1 @ wc1[:, 128:].T
  node_gemm<128, false><<<ngrid, 256, 160 * 132 * 4, stream>>>(
      h1, nullptr, wc1 + 128, 256, nullptr, nullptr,
      nullptr, nullptr, nullptr, nullptr, 0, Q);

  edge_cls<<<E_EDGES / 16, 256, 0, stream>>>(P, Q, eli, wc2, bc2, (float*)d_out);
}